// Round 4
// baseline (914.907 us; speedup 1.0000x reference)
//
#include <hip/hip_runtime.h>
#include <hip/hip_fp16.h>

typedef __attribute__((ext_vector_type(8))) short s16x8;
typedef __attribute__((ext_vector_type(4))) short s16x4;
typedef __attribute__((ext_vector_type(4))) float f32x4;
typedef __attribute__((ext_vector_type(8))) _Float16 h16x8;
typedef __attribute__((ext_vector_type(2))) __fp16 fp16x2;

#define MFMA16(a, b, c) __builtin_amdgcn_mfma_f32_16x16x32_f16(a, b, c, 0, 0, 0)

static __device__ __forceinline__ h16x8 as_h(s16x8 v) {
  union { s16x8 s; h16x8 h; } u; u.s = v; return u.h;
}
static __device__ __forceinline__ unsigned short h16b(float f) {
  return __half_as_ushort(__float2half(f));  // RNE
}
static __device__ __forceinline__ unsigned pack2h(float a, float b) {
  union { fp16x2 h; unsigned u; } u;
  u.h = __builtin_amdgcn_cvt_pkrtz(a, b);   // v_cvt_pkrtz_f16_f32
  return u.u;
}

// ---------------- f32 -> fp16 cast ----------------
__global__ __launch_bounds__(256) void cast_f16(const float* __restrict__ in,
                                                short* __restrict__ out, int n) {
  int i = (blockIdx.x * 256 + threadIdx.x) * 4;
  if (i >= n) return;
  float4 v = *(const float4*)(in + i);
  s16x4 o;
  o[0] = (short)h16b(v.x);
  o[1] = (short)h16b(v.y);
  o[2] = (short)h16b(v.z);
  o[3] = (short)h16b(v.w);
  *(s16x4*)(out + i) = o;
}

// ---------------- GEMM: C[M,N] = A[M,K] * B[N,K]^T (both K-major, fp16 in) ----
// MODE 0: scatter-epilogue into q/k/v [B,H,S,HD] as fp16 (QKV projection)
// MODE 1: plain f32 row-major output (final projection)
template <int MODE>
__global__ __launch_bounds__(256) void gemm_bt(const short* __restrict__ A,
                                               const short* __restrict__ Bm,
                                               int M, int N, int K,
                                               short* __restrict__ oq,
                                               short* __restrict__ ok,
                                               short* __restrict__ ov,
                                               float* __restrict__ of) {
  // 40-short rows (80 B) -> b128 quads spread across bank groups
  __shared__ short Ash[128][40];
  __shared__ short Bsh[128][40];
  const int tid = threadIdx.x;
  const int wave = tid >> 6, lane = tid & 63;
  const int g = lane >> 4, qi = lane & 15;
  const int wm = wave >> 1, wn = wave & 1;
  const int m0 = blockIdx.y * 128, n0 = blockIdx.x * 128;

  f32x4 acc[4][4] = {};

  for (int k0 = 0; k0 < K; k0 += 32) {
    __syncthreads();
    for (int c = tid; c < 512; c += 256) {
      int row = c >> 2, col8 = (c & 3) << 3;
      *(s16x8*)&Ash[row][col8] = *(const s16x8*)(A + (size_t)(m0 + row) * K + k0 + col8);
      *(s16x8*)&Bsh[row][col8] = *(const s16x8*)(Bm + (size_t)(n0 + row) * K + k0 + col8);
    }
    __syncthreads();
    s16x8 af[4], bf[4];
#pragma unroll
    for (int f = 0; f < 4; ++f) {
      af[f] = *(const s16x8*)&Ash[wm * 64 + f * 16 + qi][g * 8];
      bf[f] = *(const s16x8*)&Bsh[wn * 64 + f * 16 + qi][g * 8];
    }
#pragma unroll
    for (int fm = 0; fm < 4; ++fm)
#pragma unroll
      for (int fn = 0; fn < 4; ++fn)
        acc[fm][fn] = MFMA16(as_h(af[fm]), as_h(bf[fn]), acc[fm][fn]);
  }

  const int rbase = m0 + wm * 64, cbase = n0 + wn * 64;
#pragma unroll
  for (int fm = 0; fm < 4; ++fm) {
#pragma unroll
    for (int fn = 0; fn < 4; ++fn) {
#pragma unroll
      for (int i = 0; i < 4; ++i) {
        int r = rbase + fm * 16 + g * 4 + i;   // C/D row = (lane>>4)*4 + reg
        int c = cbase + fn * 16 + qi;          // C/D col = lane&15
        float v = acc[fm][fn][i];
        if (MODE == 0) {
          int cc = c >> 10, h = (c >> 6) & 15, hd = c & 63;
          int b = r >> 11, s = r & 2047;
          size_t idx = ((size_t)((b * 16 + h) * 2048 + s)) * 64 + hd;
          short* dst = cc == 0 ? oq : (cc == 1 ? ok : ov);
          dst[idx] = (short)h16b(v);
        } else {
          of[(size_t)r * N + c] = v;
        }
      }
    }
  }
}

// ---------------- fused bias-masked flash attention (fp16 MFMA, f32 softmax) --
// Block: 256 thr = 4 waves; one (b,h), QBLK=64 (16 q-rows per wave).
// Computes S^T = mfma(K, Q) so q lands in C cols (lane&15);
// online softmax across the 4 lane-groups via shfl_xor 16/32.
__global__ __launch_bounds__(256) void attn(const short* __restrict__ qg,
                                            const short* __restrict__ kg,
                                            const short* __restrict__ vg,
                                            const float* __restrict__ bias,
                                            const int* __restrict__ mask,
                                            short* __restrict__ aout) {
  __shared__ short Vt[64][72];  // V^T tile, 144B rows -> conflict-free b128 reads
  const int tid = threadIdx.x;
  const int wave = tid >> 6, lane = tid & 63;
  const int g = lane >> 4, qi = lane & 15;
  const int bid = blockIdx.x;
  const int qb = bid & 31, h = (bid >> 5) & 15, b = bid >> 9;
  const size_t bh = (size_t)(b * 16 + h);
  const int q0 = qb * 64 + wave * 16;
  const int qrow = q0 + qi;

  const short* qp = qg + (bh * 2048 + qrow) * 64;
  s16x8 qf0 = *(const s16x8*)(qp + g * 8);        // Q[qrow][hd 0..31]
  s16x8 qf1 = *(const s16x8*)(qp + 32 + g * 8);   // Q[qrow][hd 32..63]

  f32x4 o[4] = {};
  float m_run = -1e30f, l_run = 0.f;
  const float* brow = bias + (bh * 2048 + qrow) * 2048;
  const int* mrow = mask + b * 2048;              // bool input arrives as int32

  for (int k0 = 0; k0 < 2048; k0 += 64) {
    __syncthreads();
    // stage V^T (64 keys x 64 hd, transposed)
    for (int c = tid; c < 512; c += 256) {
      int key = c >> 3, hd8 = (c & 7) * 8;
      s16x8 vv = *(const s16x8*)(vg + (bh * 2048 + k0 + key) * 64 + hd8);
#pragma unroll
      for (int e = 0; e < 8; ++e) Vt[hd8 + e][key] = vv[e];
    }
    __syncthreads();

    // S^T[key, q]: A = K rows (16 keys/frag), B = Q (16 q cols)
    f32x4 st[4] = {};
#pragma unroll
    for (int f = 0; f < 4; ++f) {
      const short* kr = kg + (bh * 2048 + k0 + f * 16 + qi) * 64;
      s16x8 ka = *(const s16x8*)(kr + g * 8);
      s16x8 kb = *(const s16x8*)(kr + 32 + g * 8);
      st[f] = MFMA16(as_h(ka), as_h(qf0), st[f]);
      st[f] = MFMA16(as_h(kb), as_h(qf1), st[f]);
    }

    // bias + mask; lane holds keys k0 + f*16 + g*4 + i for q-row (lane&15)
    float s[16], mx = -1e30f;
#pragma unroll
    for (int f = 0; f < 4; ++f) {
      float4 bv = *(const float4*)(brow + k0 + f * 16 + g * 4);
      int4 mk = *(const int4*)(mrow + k0 + f * 16 + g * 4);
      float s0 = st[f][0] + (mk.x ? bv.x : -10000.f);
      float s1 = st[f][1] + (mk.y ? bv.y : -10000.f);
      float s2 = st[f][2] + (mk.z ? bv.z : -10000.f);
      float s3 = st[f][3] + (mk.w ? bv.w : -10000.f);
      s[f * 4 + 0] = s0; s[f * 4 + 1] = s1; s[f * 4 + 2] = s2; s[f * 4 + 3] = s3;
      mx = fmaxf(mx, fmaxf(fmaxf(s0, s1), fmaxf(s2, s3)));
    }
    mx = fmaxf(mx, __shfl_xor(mx, 16));
    mx = fmaxf(mx, __shfl_xor(mx, 32));

    float m_new = fmaxf(m_run, mx);
    float corr = __expf(m_run - m_new);
    float p[16], lsum = 0.f;
#pragma unroll
    for (int t = 0; t < 16; ++t) {
      p[t] = __expf(s[t] - m_new);
      lsum += p[t];
    }
    lsum += __shfl_xor(lsum, 16);
    lsum += __shfl_xor(lsum, 32);
    l_run = l_run * corr + lsum;
    m_run = m_new;
#pragma unroll
    for (int fh = 0; fh < 4; ++fh) {
      o[fh][0] *= corr; o[fh][1] *= corr; o[fh][2] *= corr; o[fh][3] *= corr;
    }

    // P (f32, S^T C-layout) -> fp16 B-frags P^T for PV, via packed shuffles
    unsigned lo[4], hi[4];
#pragma unroll
    for (int f = 0; f < 4; ++f) {
      lo[f] = pack2h(p[f * 4 + 0], p[f * 4 + 1]);
      hi[f] = pack2h(p[f * 4 + 2], p[f * 4 + 3]);
    }
    const int sl0 = (2 * (g & 1)) * 16 + qi;
    const bool fs = ((g >> 1) & 1) != 0;
    s16x8 pb[2];
#pragma unroll
    for (int kk = 0; kk < 2; ++kk) {
      unsigned la0 = __shfl(lo[2 * kk], sl0),      la1 = __shfl(lo[2 * kk + 1], sl0);
      unsigned ha0 = __shfl(hi[2 * kk], sl0),      ha1 = __shfl(hi[2 * kk + 1], sl0);
      unsigned lb0 = __shfl(lo[2 * kk], sl0 + 16), lb1 = __shfl(lo[2 * kk + 1], sl0 + 16);
      unsigned hb0 = __shfl(hi[2 * kk], sl0 + 16), hb1 = __shfl(hi[2 * kk + 1], sl0 + 16);
      union { unsigned u[4]; s16x8 v; } pu;
      pu.u[0] = fs ? la1 : la0;
      pu.u[1] = fs ? ha1 : ha0;
      pu.u[2] = fs ? lb1 : lb0;
      pu.u[3] = fs ? hb1 : hb0;
      pb[kk] = pu.v;
    }

    // O^T[hd, q] += V^T[hd, key] * P^T[key, q]
#pragma unroll
    for (int fh = 0; fh < 4; ++fh) {
#pragma unroll
      for (int kk = 0; kk < 2; ++kk) {
        s16x8 va = *(const s16x8*)&Vt[fh * 16 + qi][kk * 32 + g * 8];
        o[fh] = MFMA16(as_h(va), as_h(pb[kk]), o[fh]);
      }
    }
  }

  float inv = 1.f / l_run;
  short* ar = aout + ((size_t)b * 2048 + qrow) * 1024 + h * 64;
#pragma unroll
  for (int fh = 0; fh < 4; ++fh)
#pragma unroll
    for (int i = 0; i < 4; ++i)
      ar[fh * 16 + g * 4 + i] = (short)h16b(o[fh][i] * inv);
}

extern "C" void kernel_launch(void* const* d_in, const int* in_sizes, int n_in,
                              void* d_out, int out_size, void* d_ws, size_t ws_size,
                              hipStream_t stream) {
  const float* x = (const float*)d_in[0];
  const float* bias = (const float*)d_in[1];
  const int* mask = (const int*)d_in[2];   // bool -> int32 in harness
  const float* wqkv = (const float*)d_in[3];
  const float* wo = (const float*)d_in[4];
  float* out = (float*)d_out;

  char* w = (char*)d_ws;
  short* xb    = (short*)(w);
  short* wqkvb = (short*)(w + (8ull << 20));
  short* wob   = (short*)(w + (14ull << 20));
  short* qb    = (short*)(w + (16ull << 20));
  short* kb    = (short*)(w + (24ull << 20));
  short* vb    = (short*)(w + (32ull << 20));
  short* ab    = (short*)(w + (40ull << 20));

  cast_f16<<<4096, 256, 0, stream>>>(x, xb, 4194304);
  cast_f16<<<3072, 256, 0, stream>>>(wqkv, wqkvb, 3145728);
  cast_f16<<<1024, 256, 0, stream>>>(wo, wob, 1048576);

  // qkv = x @ Wqkv^T, scattered to q/k/v [B,H,S,HD] fp16
  gemm_bt<0><<<dim3(24, 32), 256, 0, stream>>>(xb, wqkvb, 4096, 3072, 1024,
                                               qb, kb, vb, nullptr);
  // fused masked-bias flash attention -> a [B,S,H*HD] fp16
  attn<<<1024, 256, 0, stream>>>(qb, kb, vb, bias, mask, ab);
  // out = a @ Wo^T (f32)
  gemm_bt<1><<<dim3(8, 32), 256, 0, stream>>>(ab, wob, 4096, 1024, 1024,
                                              nullptr, nullptr, nullptr, out);
}